// Round 2
// baseline (1116.919 us; speedup 1.0000x reference)
//
#include <hip/hip_runtime.h>
#include <hip/hip_bf16.h>

#define DIV_UP(a, b) (((a) + (b) - 1) / (b))

// ---------- runtime-dtype helpers ----------
// bf=1: p is packed bf16; bf=0: p is f32
__device__ __forceinline__ float ldf(const void* p, long long i, int bf) {
    return bf ? __bfloat162float(((const __hip_bfloat16*)p)[i]) : ((const float*)p)[i];
}
// w=1: p is int64 viewed as int32 pairs (little-endian, nonneg < 2^31); w=0: int32
__device__ __forceinline__ int ldi(const int* p, long long i, int w) {
    return w ? p[2 * i] : p[i];
}

// ---- ordered-uint encoding for float atomicMax ----
__device__ __forceinline__ unsigned fenc(float f) {
    unsigned u = __float_as_uint(f);
    return (u & 0x80000000u) ? ~u : (u | 0x80000000u);
}
__device__ __forceinline__ float fdec(unsigned u) {
    unsigned v = (u & 0x80000000u) ? (u & 0x7FFFFFFFu) : ~u;
    return __uint_as_float(v);
}
#define ENC_NEG_INF 0x007FFFFFu  // fenc(-inf)

// ---------------- dtype detection ----------------
// flags[0]=1 iff float tensors are bf16-packed; flags[1]=1 iff ints are int64.
__global__ void k_detect(const unsigned* __restrict__ xb, const unsigned* __restrict__ eb,
                         int* __restrict__ flags) {
    if (threadIdx.x != 0 || blockIdx.x != 0) return;
    int votes = 0;
#pragma unroll 8
    for (int i = 0; i < 256; ++i) {
        unsigned e = (xb[i] >> 7) & 0xFFu;  // low-half bf16 exponent field
        votes += (e >= 115u && e <= 133u) ? 1 : 0;
    }
    flags[0] = (votes > 128) ? 1 : 0;
    int zeros = 0;
#pragma unroll 8
    for (int i = 0; i < 256; ++i) zeros += (eb[2 * i + 1] == 0u) ? 1 : 0;
    flags[1] = (zeros > 200) ? 1 : 0;
}

// ---------------- degree / dinv ----------------
__global__ void k_deg_init(float* deg, int N) {
    int t = blockIdx.x * blockDim.x + threadIdx.x;
    if (t < N) deg[t] = 1.0f;  // self-loop
}
__global__ void k_deg_acc(const int* __restrict__ ei, float* deg, const int* __restrict__ flags,
                          int E) {
    int t = blockIdx.x * blockDim.x + threadIdx.x;
    if (t >= E) return;
    int wi = flags[1];
    int d = ldi(ei, (long long)E + t, wi);  // dst row follows src row
    atomicAdd(&deg[d], 1.0f);
}
__global__ void k_dinv(float* deg, int N) {
    int t = blockIdx.x * blockDim.x + threadIdx.x;
    if (t < N) deg[t] = rsqrtf(deg[t]);  // deg >= 1 always
}

// ---------------- self-loop init: Y[n,k] = dinv[n]^2 * X[n,k] ----------------
// EXT=true: X is an external input (use flags[0]); EXT=false: X is internal f32.
template <int K, bool EXT>
__global__ void k_self(const void* __restrict__ X, const float* __restrict__ dinv,
                       float* __restrict__ Y, const int* __restrict__ flags, int N) {
    int t = blockIdx.x * blockDim.x + threadIdx.x;
    if (t >= N * K) return;
    int bf = EXT ? flags[0] : 0;
    int n = t / K;
    float di = dinv[n];
    Y[t] = di * di * ldf(X, t, bf);
}

// ---------------- edge scatter: Y[dst,k] += dinv[s]*dinv[d]*X[src,k] ----------------
template <int K, bool EXT>
__global__ void k_edge(const void* __restrict__ X, float* __restrict__ Y,
                       const int* __restrict__ ei, const float* __restrict__ dinv,
                       const int* __restrict__ flags, int E) {
    int t = blockIdx.x * blockDim.x + threadIdx.x;
    if (t >= E * K) return;
    int bf = EXT ? flags[0] : 0;
    int wi = flags[1];
    int e = t / K;
    int k = t - e * K;
    int s = ldi(ei, e, wi);
    int d = ldi(ei, (long long)E + e, wi);
    float w = dinv[s] * dinv[d];
    atomicAdd(&Y[(long long)d * K + k], w * ldf(X, (long long)s * K + k, bf));
}

// ---------------- small GEMM: Y = act(X @ W + b), X/Y f32 internal ----------------
template <int IN, int OUT, bool RELU, bool BIAS>
__global__ void k_gemm(const float* __restrict__ X, const void* __restrict__ W,
                       const void* __restrict__ b, float* __restrict__ Y,
                       const int* __restrict__ flags, int N) {
    __shared__ float Ws[IN * OUT];
    __shared__ float bs[OUT];
    int bf = flags[0];
    for (int i = threadIdx.x; i < IN * OUT; i += blockDim.x) Ws[i] = ldf(W, i, bf);
    if (BIAS)
        for (int i = threadIdx.x; i < OUT; i += blockDim.x) bs[i] = ldf(b, i, bf);
    __syncthreads();
    int t = blockIdx.x * blockDim.x + threadIdx.x;
    if (t >= N * OUT) return;
    int n = t / OUT;
    int o = t - n * OUT;
    const float* xr = X + (long long)n * IN;
    float acc = BIAS ? bs[o] : 0.0f;
#pragma unroll
    for (int k = 0; k < IN; ++k) acc = fmaf(xr[k], Ws[k * OUT + o], acc);
    Y[t] = RELU ? fmaxf(acc, 0.0f) : acc;
}

// ---------------- pooled init ----------------
__global__ void k_pool_init(unsigned* pooled) {
    int t = threadIdx.x;
    if (t < 64 * 3) pooled[t] = ENC_NEG_INF;
}

// ---------------- head: h3 = relu(Y3 + b3); z = h3 @ Wo + bo; segment-max ----------------
__global__ void k_head(const float* __restrict__ Y3, const void* __restrict__ b3,
                       const void* __restrict__ Wo, const void* __restrict__ bo,
                       const int* __restrict__ batch, unsigned* __restrict__ pooled,
                       const int* __restrict__ flags, int N) {
    __shared__ float Ws[50 * 3];
    __shared__ float bs[50];
    __shared__ float bos[3];
    int bf = flags[0];
    int wi = flags[1];
    for (int i = threadIdx.x; i < 150; i += blockDim.x) Ws[i] = ldf(Wo, i, bf);
    for (int i = threadIdx.x; i < 50; i += blockDim.x) bs[i] = ldf(b3, i, bf);
    if (threadIdx.x < 3) bos[threadIdx.x] = ldf(bo, threadIdx.x, bf);
    __syncthreads();
    int n = blockIdx.x * blockDim.x + threadIdx.x;
    if (n >= N) return;
    float z0 = bos[0], z1 = bos[1], z2 = bos[2];
    const float* y = Y3 + (long long)n * 50;
#pragma unroll
    for (int k = 0; k < 50; ++k) {
        float h = fmaxf(y[k] + bs[k], 0.0f);
        z0 = fmaf(h, Ws[k * 3 + 0], z0);
        z1 = fmaf(h, Ws[k * 3 + 1], z1);
        z2 = fmaf(h, Ws[k * 3 + 2], z2);
    }
    int g = ldi(batch, n, wi);
    atomicMax(&pooled[g * 3 + 0], fenc(z0));
    atomicMax(&pooled[g * 3 + 1], fenc(z1));
    atomicMax(&pooled[g * 3 + 2], fenc(z2));
}

// ---------------- softmax over [64,3]; output dtype follows flags[0] ----------------
__global__ void k_softmax(const unsigned* __restrict__ pooled, void* __restrict__ out,
                          const int* __restrict__ flags) {
    int g = threadIdx.x;
    if (g >= 64) return;
    int bf = flags[0];
    float a = fdec(pooled[g * 3 + 0]);
    float b = fdec(pooled[g * 3 + 1]);
    float c = fdec(pooled[g * 3 + 2]);
    float m = fmaxf(a, fmaxf(b, c));
    float ea = __expf(a - m), eb = __expf(b - m), ec = __expf(c - m);
    float s = 1.0f / (ea + eb + ec);
    if (bf) {
        __hip_bfloat16* o = (__hip_bfloat16*)out;
        o[g * 3 + 0] = __float2bfloat16(ea * s);
        o[g * 3 + 1] = __float2bfloat16(eb * s);
        o[g * 3 + 2] = __float2bfloat16(ec * s);
    } else {
        float* o = (float*)out;
        o[g * 3 + 0] = ea * s;
        o[g * 3 + 1] = eb * s;
        o[g * 3 + 2] = ec * s;
    }
}

extern "C" void kernel_launch(void* const* d_in, const int* in_sizes, int n_in,
                              void* d_out, int out_size, void* d_ws, size_t ws_size,
                              hipStream_t stream) {
    const void* x = d_in[0];
    const int* ei = (const int*)d_in[1];
    const int* batch = (const int*)d_in[2];
    const void* W1 = d_in[3];
    const void* b1 = d_in[4];
    const void* W2 = d_in[5];
    const void* b2 = d_in[6];
    const void* W3 = d_in[7];
    const void* b3 = d_in[8];
    const void* Wo = d_in[9];
    const void* bo = d_in[10];

    const int N = in_sizes[0] / 36;  // element count is dtype-independent
    const int E = in_sizes[1] / 2;

    // workspace layout (f32 internals): flags | dinv[N] | bufS[N*75] | bufL[N*150] | pooled[192]
    char* ws = (char*)d_ws;
    int* flags = (int*)ws;
    float* dinv = (float*)(ws + 16);
    float* bufS = dinv + N;
    float* bufL = bufS + (size_t)N * 75;
    unsigned* pooled = (unsigned*)(bufL + (size_t)N * 150);

    const int B = 256;

    // 0. dtype detection (device-side, no host sync)
    k_detect<<<1, 64, 0, stream>>>((const unsigned*)x, (const unsigned*)ei, flags);

    // 1. degree -> dinv
    k_deg_init<<<DIV_UP(N, B), B, 0, stream>>>(dinv, N);
    k_deg_acc<<<DIV_UP(E, B), B, 0, stream>>>(ei, dinv, flags, E);
    k_dinv<<<DIV_UP(N, B), B, 0, stream>>>(dinv, N);

    // 2. layer 1: aggregate x (36) -> bufS, then GEMM 36->75 -> bufL
    k_self<36, true><<<DIV_UP(N * 36, B), B, 0, stream>>>(x, dinv, bufS, flags, N);
    k_edge<36, true><<<DIV_UP(E * 36, B), B, 0, stream>>>(x, bufS, ei, dinv, flags, E);
    k_gemm<36, 75, true, true><<<DIV_UP(N * 75, B), B, 0, stream>>>(bufS, W1, b1, bufL, flags, N);

    // 3. layer 2: aggregate h1 (75) -> bufS, then GEMM 75->150 -> bufL
    k_self<75, false><<<DIV_UP(N * 75, B), B, 0, stream>>>(bufL, dinv, bufS, flags, N);
    k_edge<75, false><<<DIV_UP(E * 75, B), B, 0, stream>>>(bufL, bufS, ei, dinv, flags, E);
    k_gemm<75, 150, true, true><<<DIV_UP(N * 150, B), B, 0, stream>>>(bufS, W2, b2, bufL, flags, N);

    // 4. layer 3: GEMM first 150->50 -> bufS, then aggregate (50) -> bufL
    k_gemm<150, 50, false, false><<<DIV_UP(N * 50, B), B, 0, stream>>>(bufL, W3, nullptr, bufS,
                                                                      flags, N);
    k_self<50, false><<<DIV_UP(N * 50, B), B, 0, stream>>>(bufS, dinv, bufL, flags, N);
    k_edge<50, false><<<DIV_UP(E * 50, B), B, 0, stream>>>(bufS, bufL, ei, dinv, flags, E);

    // 5. head + pooling + softmax
    k_pool_init<<<1, 192, 0, stream>>>(pooled);
    k_head<<<DIV_UP(N, B), B, 0, stream>>>(bufL, b3, Wo, bo, batch, pooled, flags, N);
    k_softmax<<<1, 64, 0, stream>>>(pooled, d_out, flags);
}

// Round 3
// 996.373 us; speedup vs baseline: 1.1210x; 1.1210x over previous
//
#include <hip/hip_runtime.h>
#include <hip/hip_bf16.h>

#define DIV_UP(a, b) (((a) + (b) - 1) / (b))
typedef long long ll;

// ---------- runtime-dtype helpers ----------
__device__ __forceinline__ float ldf(const void* p, ll i, int bf) {
    return bf ? __bfloat162float(((const __hip_bfloat16*)p)[i]) : ((const float*)p)[i];
}
__device__ __forceinline__ int ldi(const int* p, ll i, int w) {
    return w ? p[2 * i] : p[i];
}
template <bool BF16>
__device__ __forceinline__ float ldx(const void* p, ll i) {
    return BF16 ? __bfloat162float(((const __hip_bfloat16*)p)[i]) : ((const float*)p)[i];
}
template <bool BF16>
__device__ __forceinline__ void stf(void* p, ll i, float v) {
    if (BF16)
        ((__hip_bfloat16*)p)[i] = __float2bfloat16(v);
    else
        ((float*)p)[i] = v;
}

// ---- ordered-uint encoding for float atomicMax ----
__device__ __forceinline__ unsigned fenc(float f) {
    unsigned u = __float_as_uint(f);
    return (u & 0x80000000u) ? ~u : (u | 0x80000000u);
}
__device__ __forceinline__ float fdec(unsigned u) {
    unsigned v = (u & 0x80000000u) ? (u & 0x7FFFFFFFu) : ~u;
    return __uint_as_float(v);
}
#define ENC_NEG_INF 0x007FFFFFu

// ---------------- dtype detection ----------------
__global__ void k_detect(const unsigned* __restrict__ xb, const unsigned* __restrict__ eb,
                         int* __restrict__ flags) {
    if (threadIdx.x != 0 || blockIdx.x != 0) return;
    int votes = 0;
    for (int i = 0; i < 256; ++i) {
        unsigned e = (xb[i] >> 7) & 0xFFu;
        votes += (e >= 115u && e <= 133u) ? 1 : 0;
    }
    flags[0] = (votes > 128) ? 1 : 0;
    int zeros = 0;
    for (int i = 0; i < 256; ++i) zeros += (eb[2 * i + 1] == 0u) ? 1 : 0;
    flags[1] = (zeros > 200) ? 1 : 0;
}

// ---------------- CSR build ----------------
__global__ void k_zero(int* p, int n) {
    int t = blockIdx.x * blockDim.x + threadIdx.x;
    if (t < n) p[t] = 0;
}
__global__ void k_hist(const int* __restrict__ ei, int* __restrict__ cnt,
                       const int* __restrict__ flags, int E) {
    int t = blockIdx.x * blockDim.x + threadIdx.x;
    if (t >= E) return;
    atomicAdd(&cnt[ldi(ei, (ll)E + t, flags[1])], 1);
}
__global__ void k_dinvc(const int* __restrict__ cnt, float* __restrict__ dinv, int N) {
    int t = blockIdx.x * blockDim.x + threadIdx.x;
    if (t < N) dinv[t] = rsqrtf((float)cnt[t] + 1.0f);  // +1 self-loop
}
// single-block exclusive scan: cnt[N] -> rowptr[N+1]
__global__ void k_scan(const int* __restrict__ cnt, int* __restrict__ rowptr, int N) {
    __shared__ int sums[1024];
    const int tid = threadIdx.x;
    const int CH = (N + 1023) >> 10;
    const int base = tid * CH;
    int s = 0;
    for (int i = 0; i < CH; ++i) {
        int idx = base + i;
        if (idx < N) s += cnt[idx];
    }
    sums[tid] = s;
    __syncthreads();
    for (int off = 1; off < 1024; off <<= 1) {
        int v = (tid >= off) ? sums[tid - off] : 0;
        __syncthreads();
        sums[tid] += v;
        __syncthreads();
    }
    int run = (tid > 0) ? sums[tid - 1] : 0;
    for (int i = 0; i < CH; ++i) {
        int idx = base + i;
        if (idx <= N) rowptr[idx] = run;
        if (idx < N) run += cnt[idx];
    }
}
__global__ void k_fill(const int* __restrict__ ei, const int* __restrict__ rowptr,
                       int* __restrict__ cursor, int* __restrict__ esrc, float* __restrict__ ew,
                       const float* __restrict__ dinv, const int* __restrict__ flags, int E) {
    int t = blockIdx.x * blockDim.x + threadIdx.x;
    if (t >= E) return;
    int wi = flags[1];
    int s = ldi(ei, t, wi);
    int d = ldi(ei, (ll)E + t, wi);
    int pos = rowptr[d] + atomicAdd(&cursor[d], 1);
    esrc[pos] = s;
    ew[pos] = dinv[s] * dinv[d];
}

// ---------------- CSR aggregation: Y[n] = dinv[n]^2*X[n] + sum_e w_e * X[src_e] ----------------
// wave per node; C <= 128
template <bool EXT>
__global__ void k_agg(const void* __restrict__ X, int xstride, float* __restrict__ Y, int ystride,
                      int C, const int* __restrict__ rowptr, const int* __restrict__ esrc,
                      const float* __restrict__ ew, const float* __restrict__ dinv,
                      const int* __restrict__ flags, int N) {
    int n = blockIdx.x * 4 + (threadIdx.x >> 6);
    if (n >= N) return;
    int lane = threadIdx.x & 63;
    int bf = EXT ? flags[0] : 0;
    float di = dinv[n];
    float w0 = di * di;
    int c1 = lane + 64;
    bool has0 = lane < C, has1 = c1 < C;
    float a0 = has0 ? w0 * ldf(X, (ll)n * xstride + lane, bf) : 0.0f;
    float a1 = has1 ? w0 * ldf(X, (ll)n * xstride + c1, bf) : 0.0f;
    int je = rowptr[n + 1];
    for (int j = rowptr[n]; j < je; ++j) {
        int s = esrc[j];
        float w = ew[j];
        if (has0) a0 = fmaf(w, ldf(X, (ll)s * xstride + lane, bf), a0);
        if (has1) a1 = fmaf(w, ldf(X, (ll)s * xstride + c1, bf), a1);
    }
    if (has0) Y[(ll)n * ystride + lane] = a0;
    if (has1) Y[(ll)n * ystride + c1] = a1;
}

// ---------------- register-tiled GEMM: Y = act(X @ W + b) ----------------
// block = 256 threads = 64 nodes; thread: 4 nodes x RN outs. Padded tiles, guarded edges.
template <int KP, int OUT, int RN, bool RELU, bool BIAS, bool BF16_IN, bool BF16_OUT>
__global__ __launch_bounds__(256) void k_gemm(const void* __restrict__ Xv, int xstride,
                                              void* __restrict__ Yv, int ystride,
                                              const void* __restrict__ W,
                                              const void* __restrict__ bias,
                                              const int* __restrict__ flags, int N) {
    constexpr int OUTP = 16 * RN;
    constexpr int BK = 40;
    constexpr int NCH = (KP + BK - 1) / BK;
    __shared__ float Xs[BK][68];  // [k][node], padded row to 68 (16B-aligned, conflict-light)
    __shared__ float Ws[BK][OUTP];
    const int tid = threadIdx.x;
    const int tn = tid & 15, to = tid >> 4;
    const int node0 = blockIdx.x * 64;
    const int bf = flags[0];
    float acc[4][RN];
#pragma unroll
    for (int m = 0; m < 4; ++m)
#pragma unroll
        for (int j = 0; j < RN; ++j) acc[m][j] = 0.0f;
    float bv[RN];
#pragma unroll
    for (int j = 0; j < RN; ++j) {
        int o = to * RN + j;
        bv[j] = (BIAS && o < OUT) ? ldf(bias, o, bf) : 0.0f;
    }
    const int nn = tid >> 2;        // node within tile for X staging
    const int kb = (tid & 3) * 10;  // k sub-range for X staging
    for (int c = 0; c < NCH; ++c) {
        const int k0 = c * BK;
        __syncthreads();
        {
            int n = node0 + nn;
#pragma unroll
            for (int i = 0; i < 10; ++i) {
                int k = kb + i;
                float v = 0.0f;
                if (n < N && (k0 + k) < KP) v = ldx<BF16_IN>(Xv, (ll)n * xstride + k0 + k);
                Xs[k][nn] = v;
            }
        }
        for (int idx = tid; idx < BK * OUTP; idx += 256) {
            int k = idx / OUTP, o = idx - k * OUTP;
            int kg = k0 + k;
            float v = 0.0f;
            if (kg < KP && o < OUT) v = ldf(W, (ll)kg * OUT + o, bf);
            Ws[k][o] = v;
        }
        __syncthreads();
        for (int k = 0; k < BK; ++k) {
            float4 x4 = *(const float4*)&Xs[k][tn * 4];
            float wv[RN];
#pragma unroll
            for (int j = 0; j < RN; ++j) wv[j] = Ws[k][to * RN + j];
#pragma unroll
            for (int j = 0; j < RN; ++j) {
                acc[0][j] = fmaf(x4.x, wv[j], acc[0][j]);
                acc[1][j] = fmaf(x4.y, wv[j], acc[1][j]);
                acc[2][j] = fmaf(x4.z, wv[j], acc[2][j]);
                acc[3][j] = fmaf(x4.w, wv[j], acc[3][j]);
            }
        }
    }
#pragma unroll
    for (int m = 0; m < 4; ++m) {
        int n = node0 + tn * 4 + m;
        if (n >= N) continue;
#pragma unroll
        for (int j = 0; j < RN; ++j) {
            int o = to * RN + j;
            if (o >= OUT) continue;
            float v = acc[m][j] + bv[j];
            if (RELU) v = fmaxf(v, 0.0f);
            stf<BF16_OUT>(Yv, (ll)n * ystride + o, v);
        }
    }
}

// ---------------- pooled init ----------------
__global__ void k_pool_init(unsigned* pooled) {
    int t = threadIdx.x;
    if (t < 64 * 3) pooled[t] = ENC_NEG_INF;
}

// ---------------- head: z = relu(Y3 + b3) @ Wo + bo; segment-max ----------------
__global__ void k_head(const float* __restrict__ Y3, int ystride, const void* __restrict__ b3,
                       const void* __restrict__ Wo, const void* __restrict__ bo,
                       const int* __restrict__ batch, unsigned* __restrict__ pooled,
                       const int* __restrict__ flags, int N) {
    __shared__ float Ws[50 * 3];
    __shared__ float bs[50];
    __shared__ float bos[3];
    int bf = flags[0];
    int wi = flags[1];
    for (int i = threadIdx.x; i < 150; i += blockDim.x) Ws[i] = ldf(Wo, i, bf);
    for (int i = threadIdx.x; i < 50; i += blockDim.x) bs[i] = ldf(b3, i, bf);
    if (threadIdx.x < 3) bos[threadIdx.x] = ldf(bo, threadIdx.x, bf);
    __syncthreads();
    int n = blockIdx.x * blockDim.x + threadIdx.x;
    if (n >= N) return;
    float z0 = bos[0], z1 = bos[1], z2 = bos[2];
    const float* y = Y3 + (ll)n * ystride;
#pragma unroll
    for (int k = 0; k < 50; ++k) {
        float h = fmaxf(y[k] + bs[k], 0.0f);
        z0 = fmaf(h, Ws[k * 3 + 0], z0);
        z1 = fmaf(h, Ws[k * 3 + 1], z1);
        z2 = fmaf(h, Ws[k * 3 + 2], z2);
    }
    int g = ldi(batch, n, wi);
    atomicMax(&pooled[g * 3 + 0], fenc(z0));
    atomicMax(&pooled[g * 3 + 1], fenc(z1));
    atomicMax(&pooled[g * 3 + 2], fenc(z2));
}

// ---------------- softmax over [64,3] ----------------
__global__ void k_softmax(const unsigned* __restrict__ pooled, void* __restrict__ out,
                          const int* __restrict__ flags) {
    int g = threadIdx.x;
    if (g >= 64) return;
    int bf = flags[0];
    float a = fdec(pooled[g * 3 + 0]);
    float b = fdec(pooled[g * 3 + 1]);
    float c = fdec(pooled[g * 3 + 2]);
    float m = fmaxf(a, fmaxf(b, c));
    float ea = __expf(a - m), eb = __expf(b - m), ec = __expf(c - m);
    float s = 1.0f / (ea + eb + ec);
    if (bf) {
        __hip_bfloat16* o = (__hip_bfloat16*)out;
        o[g * 3 + 0] = __float2bfloat16(ea * s);
        o[g * 3 + 1] = __float2bfloat16(eb * s);
        o[g * 3 + 2] = __float2bfloat16(ec * s);
    } else {
        float* o = (float*)out;
        o[g * 3 + 0] = ea * s;
        o[g * 3 + 1] = eb * s;
        o[g * 3 + 2] = ec * s;
    }
}

extern "C" void kernel_launch(void* const* d_in, const int* in_sizes, int n_in,
                              void* d_out, int out_size, void* d_ws, size_t ws_size,
                              hipStream_t stream) {
    const void* x = d_in[0];
    const int* ei = (const int*)d_in[1];
    const int* batch = (const int*)d_in[2];
    const void* W1 = d_in[3];
    const void* b1 = d_in[4];
    const void* W2 = d_in[5];
    const void* b2 = d_in[6];
    const void* W3 = d_in[7];
    const void* b3 = d_in[8];
    const void* Wo = d_in[9];
    const void* bo = d_in[10];

    const int N = in_sizes[0] / 36;
    const int E = in_sizes[1] / 2;

    // ---- workspace carve (total ~34 MB) ----
    char* ws = (char*)d_ws;
    size_t off = 0;
    auto carve = [&](size_t bytes) {
        char* p = ws + off;
        off = (off + bytes + 255) & ~(size_t)255;
        return p;
    };
    int* flags = (int*)carve(16);
    float* dinv = (float*)carve((size_t)N * 4);
    int* cnt = (int*)carve((size_t)N * 4);  // histogram, then cursor
    int* rowptr = (int*)carve((size_t)(N + 1) * 4);
    int* esrc = (int*)carve((size_t)E * 4);
    float* ew = (float*)carve((size_t)E * 4);
    unsigned* pooled = (unsigned*)carve(768);
    char* R1 = carve((size_t)N * 304);  // A1 f32 s76 | A2 f32 s76 | T3 f32 s76
    char* R2 = carve((size_t)N * 304);  // H1 f32 s76 | H2 bf16 s152 | Y3 f32 s76

    const int B = 256;

    // 0. dtype detection
    k_detect<<<1, 64, 0, stream>>>((const unsigned*)x, (const unsigned*)ei, flags);

    // 1. CSR build
    k_zero<<<DIV_UP(N, B), B, 0, stream>>>(cnt, N);
    k_hist<<<DIV_UP(E, B), B, 0, stream>>>(ei, cnt, flags, E);
    k_dinvc<<<DIV_UP(N, B), B, 0, stream>>>(cnt, dinv, N);
    k_scan<<<1, 1024, 0, stream>>>(cnt, rowptr, N);
    k_zero<<<DIV_UP(N, B), B, 0, stream>>>(cnt, N);
    k_fill<<<DIV_UP(E, B), B, 0, stream>>>(ei, rowptr, cnt, esrc, ew, dinv, flags, E);

    // 2. layer 1: aggregate x (36) -> A1, GEMM 36->75 relu -> H1
    k_agg<true><<<DIV_UP(N, 4), B, 0, stream>>>(x, 36, (float*)R1, 76, 36, rowptr, esrc, ew, dinv,
                                                flags, N);
    k_gemm<36, 75, 5, true, true, false, false>
        <<<DIV_UP(N, 64), B, 0, stream>>>(R1, 76, R2, 76, W1, b1, flags, N);

    // 3. layer 2: aggregate H1 (75) -> A2, GEMM 75->150 relu -> H2 (bf16)
    k_agg<false><<<DIV_UP(N, 4), B, 0, stream>>>(R2, 76, (float*)R1, 76, 75, rowptr, esrc, ew, dinv,
                                                 flags, N);
    k_gemm<75, 150, 10, true, true, false, true>
        <<<DIV_UP(N, 64), B, 0, stream>>>(R1, 76, R2, 152, W2, b2, flags, N);

    // 4. layer 3: GEMM 150->50 (no act) -> T3, aggregate (50) -> Y3
    k_gemm<150, 50, 4, false, false, true, false>
        <<<DIV_UP(N, 64), B, 0, stream>>>(R2, 152, R1, 76, W3, nullptr, flags, N);
    k_agg<false><<<DIV_UP(N, 4), B, 0, stream>>>(R1, 76, (float*)R2, 76, 50, rowptr, esrc, ew, dinv,
                                                 flags, N);

    // 5. head + pooling + softmax
    k_pool_init<<<1, 192, 0, stream>>>(pooled);
    k_head<<<DIV_UP(N, B), B, 0, stream>>>((const float*)R2, 76, b3, Wo, bo, batch, pooled, flags,
                                           N);
    k_softmax<<<1, 64, 0, stream>>>(pooled, d_out, flags);
}

// Round 4
// 684.715 us; speedup vs baseline: 1.6312x; 1.4552x over previous
//
#include <hip/hip_runtime.h>
#include <hip/hip_bf16.h>

#define DIV_UP(a, b) (((a) + (b) - 1) / (b))
typedef long long ll;

// ---------- runtime-dtype helpers ----------
__device__ __forceinline__ float ldf(const void* p, ll i, int bf) {
    return bf ? __bfloat162float(((const __hip_bfloat16*)p)[i]) : ((const float*)p)[i];
}
__device__ __forceinline__ int ldi(const int* p, ll i, int w) {
    return w ? p[2 * i] : p[i];
}
template <bool BF16>
__device__ __forceinline__ float ldx(const void* p, ll i) {
    return BF16 ? __bfloat162float(((const __hip_bfloat16*)p)[i]) : ((const float*)p)[i];
}
template <bool BF16>
__device__ __forceinline__ void stf(void* p, ll i, float v) {
    if (BF16)
        ((__hip_bfloat16*)p)[i] = __float2bfloat16(v);
    else
        ((float*)p)[i] = v;
}

// ---- ordered-uint encoding for float atomicMax ----
__device__ __forceinline__ unsigned fenc(float f) {
    unsigned u = __float_as_uint(f);
    return (u & 0x80000000u) ? ~u : (u | 0x80000000u);
}
__device__ __forceinline__ float fdec(unsigned u) {
    unsigned v = (u & 0x80000000u) ? (u & 0x7FFFFFFFu) : ~u;
    return __uint_as_float(v);
}
#define ENC_NEG_INF 0x007FFFFFu

// ---------------- dtype detection (parallel, 1 block x 256) ----------------
__global__ void k_detect(const unsigned* __restrict__ xb, const unsigned* __restrict__ eb,
                         int* __restrict__ flags) {
    __shared__ int sv[2];
    int t = threadIdx.x;
    if (t < 2) sv[t] = 0;
    __syncthreads();
    unsigned e = (xb[t] >> 7) & 0xFFu;
    int vote = (e >= 115u && e <= 133u) ? 1 : 0;
    int zero = (eb[2 * t + 1] == 0u) ? 1 : 0;
    atomicAdd(&sv[0], vote);
    atomicAdd(&sv[1], zero);
    __syncthreads();
    if (t == 0) {
        flags[0] = (sv[0] > 128) ? 1 : 0;
        flags[1] = (sv[1] > 200) ? 1 : 0;
    }
}

// ---------------- CSR build ----------------
__global__ void k_zero(int* p, int n) {
    int t = blockIdx.x * blockDim.x + threadIdx.x;
    if (t < n) p[t] = 0;
}
__global__ void k_hist(const int* __restrict__ ei, int* __restrict__ cnt,
                       const int* __restrict__ flags, int E) {
    int t = blockIdx.x * blockDim.x + threadIdx.x;
    if (t >= E) return;
    atomicAdd(&cnt[ldi(ei, (ll)E + t, flags[1])], 1);
}
__global__ void k_dinvc(const int* __restrict__ cnt, float* __restrict__ dinv, int N) {
    int t = blockIdx.x * blockDim.x + threadIdx.x;
    if (t < N) dinv[t] = rsqrtf((float)cnt[t] + 1.0f);  // +1 self-loop
}
// single-block exclusive scan: cnt[N] -> rowptr[N+1]
__global__ void k_scan(const int* __restrict__ cnt, int* __restrict__ rowptr, int N) {
    __shared__ int sums[1024];
    const int tid = threadIdx.x;
    const int CH = (N + 1023) >> 10;
    const int base = tid * CH;
    int s = 0;
    for (int i = 0; i < CH; ++i) {
        int idx = base + i;
        if (idx < N) s += cnt[idx];
    }
    sums[tid] = s;
    __syncthreads();
    for (int off = 1; off < 1024; off <<= 1) {
        int v = (tid >= off) ? sums[tid - off] : 0;
        __syncthreads();
        sums[tid] += v;
        __syncthreads();
    }
    int run = (tid > 0) ? sums[tid - 1] : 0;
    for (int i = 0; i < CH; ++i) {
        int idx = base + i;
        if (idx <= N) rowptr[idx] = run;
        if (idx < N) run += cnt[idx];
    }
}
// fill interleaved (src, weight) pairs
__global__ void k_fill(const int* __restrict__ ei, const int* __restrict__ rowptr,
                       int* __restrict__ cursor, int2* __restrict__ ep,
                       const float* __restrict__ dinv, const int* __restrict__ flags, int E) {
    int t = blockIdx.x * blockDim.x + threadIdx.x;
    if (t >= E) return;
    int wi = flags[1];
    int s = ldi(ei, t, wi);
    int d = ldi(ei, (ll)E + t, wi);
    int pos = rowptr[d] + atomicAdd(&cursor[d], 1);
    int2 v;
    v.x = s;
    v.y = __float_as_int(dinv[s] * dinv[d]);
    ep[pos] = v;
}

// ---------------- CSR aggregation: Y[n] = dinv[n]^2*X[n] + sum_e w_e * X[src_e] ----------------
// wave per node; C <= 128
template <bool EXT>
__global__ void k_agg(const void* __restrict__ X, int xstride, float* __restrict__ Y, int ystride,
                      int C, const int* __restrict__ rowptr, const int2* __restrict__ ep,
                      const float* __restrict__ dinv, const int* __restrict__ flags, int N) {
    int n = blockIdx.x * 4 + (threadIdx.x >> 6);
    if (n >= N) return;
    int lane = threadIdx.x & 63;
    int bf = EXT ? flags[0] : 0;
    float di = dinv[n];
    float w0 = di * di;
    int c1 = lane + 64;
    bool has0 = lane < C, has1 = c1 < C;
    float a0 = has0 ? w0 * ldf(X, (ll)n * xstride + lane, bf) : 0.0f;
    float a1 = has1 ? w0 * ldf(X, (ll)n * xstride + c1, bf) : 0.0f;
    int j = rowptr[n];
    int je = rowptr[n + 1];
    for (; j + 1 < je; j += 2) {
        int2 v0 = ep[j];
        int2 v1 = ep[j + 1];
        int s0 = v0.x, s1 = v1.x;
        float wa = __int_as_float(v0.y), wb = __int_as_float(v1.y);
        if (has0) {
            a0 = fmaf(wa, ldf(X, (ll)s0 * xstride + lane, bf), a0);
            a0 = fmaf(wb, ldf(X, (ll)s1 * xstride + lane, bf), a0);
        }
        if (has1) {
            a1 = fmaf(wa, ldf(X, (ll)s0 * xstride + c1, bf), a1);
            a1 = fmaf(wb, ldf(X, (ll)s1 * xstride + c1, bf), a1);
        }
    }
    if (j < je) {
        int2 v0 = ep[j];
        int s0 = v0.x;
        float wa = __int_as_float(v0.y);
        if (has0) a0 = fmaf(wa, ldf(X, (ll)s0 * xstride + lane, bf), a0);
        if (has1) a1 = fmaf(wa, ldf(X, (ll)s0 * xstride + c1, bf), a1);
    }
    if (has0) Y[(ll)n * ystride + lane] = a0;
    if (has1) Y[(ll)n * ystride + c1] = a1;
}

// ---------------- register-tiled GEMM: Y = act(X @ W + b) ----------------
template <int KP, int OUT, int RN, bool RELU, bool BIAS, bool BF16_IN, bool BF16_OUT>
__global__ __launch_bounds__(256) void k_gemm(const void* __restrict__ Xv, int xstride,
                                              void* __restrict__ Yv, int ystride,
                                              const void* __restrict__ W,
                                              const void* __restrict__ bias,
                                              const int* __restrict__ flags, int N) {
    constexpr int OUTP = 16 * RN;
    constexpr int BK = 40;
    constexpr int NCH = (KP + BK - 1) / BK;
    __shared__ float Xs[BK][68];
    __shared__ float Ws[BK][OUTP];
    const int tid = threadIdx.x;
    const int tn = tid & 15, to = tid >> 4;
    const int node0 = blockIdx.x * 64;
    const int bf = flags[0];
    float acc[4][RN];
#pragma unroll
    for (int m = 0; m < 4; ++m)
#pragma unroll
        for (int j = 0; j < RN; ++j) acc[m][j] = 0.0f;
    float bv[RN];
#pragma unroll
    for (int j = 0; j < RN; ++j) {
        int o = to * RN + j;
        bv[j] = (BIAS && o < OUT) ? ldf(bias, o, bf) : 0.0f;
    }
    const int nn = tid >> 2;
    const int kb = (tid & 3) * 10;
    for (int c = 0; c < NCH; ++c) {
        const int k0 = c * BK;
        __syncthreads();
        {
            int n = node0 + nn;
#pragma unroll
            for (int i = 0; i < 10; ++i) {
                int k = kb + i;
                float v = 0.0f;
                if (n < N && (k0 + k) < KP) v = ldx<BF16_IN>(Xv, (ll)n * xstride + k0 + k);
                Xs[k][nn] = v;
            }
        }
        for (int idx = tid; idx < BK * OUTP; idx += 256) {
            int k = idx / OUTP, o = idx - k * OUTP;
            int kg = k0 + k;
            float v = 0.0f;
            if (kg < KP && o < OUT) v = ldf(W, (ll)kg * OUT + o, bf);
            Ws[k][o] = v;
        }
        __syncthreads();
        for (int k = 0; k < BK; ++k) {
            float4 x4 = *(const float4*)&Xs[k][tn * 4];
            float wv[RN];
#pragma unroll
            for (int j = 0; j < RN; ++j) wv[j] = Ws[k][to * RN + j];
#pragma unroll
            for (int j = 0; j < RN; ++j) {
                acc[0][j] = fmaf(x4.x, wv[j], acc[0][j]);
                acc[1][j] = fmaf(x4.y, wv[j], acc[1][j]);
                acc[2][j] = fmaf(x4.z, wv[j], acc[2][j]);
                acc[3][j] = fmaf(x4.w, wv[j], acc[3][j]);
            }
        }
    }
#pragma unroll
    for (int m = 0; m < 4; ++m) {
        int n = node0 + tn * 4 + m;
        if (n >= N) continue;
#pragma unroll
        for (int j = 0; j < RN; ++j) {
            int o = to * RN + j;
            if (o >= OUT) continue;
            float v = acc[m][j] + bv[j];
            if (RELU) v = fmaxf(v, 0.0f);
            stf<BF16_OUT>(Yv, (ll)n * ystride + o, v);
        }
    }
}

// ---------------- pooled init ----------------
__global__ void k_pool_init(unsigned* pooled) {
    int t = threadIdx.x;
    if (t < 64 * 3) pooled[t] = ENC_NEG_INF;
}

// ---------------- head: z = relu(Y3 + b3) @ Wo + bo; hierarchical segment-max ----------------
__global__ void k_head(const float* __restrict__ Y3, int ystride, const void* __restrict__ b3,
                       const void* __restrict__ Wo, const void* __restrict__ bo,
                       const int* __restrict__ batch, unsigned* __restrict__ pooled,
                       const int* __restrict__ flags, int N) {
    __shared__ float Ws[50 * 3];
    __shared__ float bs[50];
    __shared__ float bos[3];
    __shared__ unsigned lmax[192];
    int bf = flags[0];
    int wi = flags[1];
    for (int i = threadIdx.x; i < 150; i += blockDim.x) Ws[i] = ldf(Wo, i, bf);
    for (int i = threadIdx.x; i < 50; i += blockDim.x) bs[i] = ldf(b3, i, bf);
    if (threadIdx.x < 3) bos[threadIdx.x] = ldf(bo, threadIdx.x, bf);
    for (int i = threadIdx.x; i < 192; i += blockDim.x) lmax[i] = ENC_NEG_INF;
    __syncthreads();
    int n = blockIdx.x * blockDim.x + threadIdx.x;
    int lane = threadIdx.x & 63;
    float z0 = 0.0f, z1 = 0.0f, z2 = 0.0f;
    int g = 0;
    if (n < N) {
        z0 = bos[0];
        z1 = bos[1];
        z2 = bos[2];
        const float* y = Y3 + (ll)n * ystride;
#pragma unroll
        for (int k = 0; k < 50; ++k) {
            float h = fmaxf(y[k] + bs[k], 0.0f);
            z0 = fmaf(h, Ws[k * 3 + 0], z0);
            z1 = fmaf(h, Ws[k * 3 + 1], z1);
            z2 = fmaf(h, Ws[k * 3 + 2], z2);
        }
        g = ldi(batch, n, wi);
    }
    int g0 = __shfl(g, 0);
    unsigned long long uni = __ballot(n < N && g == g0);
    if (uni == ~0ULL) {
        // whole wave same graph: shuffle max-reduce, one LDS atomic per wave
#pragma unroll
        for (int off = 32; off > 0; off >>= 1) {
            z0 = fmaxf(z0, __shfl_xor(z0, off));
            z1 = fmaxf(z1, __shfl_xor(z1, off));
            z2 = fmaxf(z2, __shfl_xor(z2, off));
        }
        if (lane == 0) {
            atomicMax(&lmax[g0 * 3 + 0], fenc(z0));
            atomicMax(&lmax[g0 * 3 + 1], fenc(z1));
            atomicMax(&lmax[g0 * 3 + 2], fenc(z2));
        }
    } else if (n < N) {
        atomicMax(&lmax[g * 3 + 0], fenc(z0));
        atomicMax(&lmax[g * 3 + 1], fenc(z1));
        atomicMax(&lmax[g * 3 + 2], fenc(z2));
    }
    __syncthreads();
    for (int i = threadIdx.x; i < 192; i += blockDim.x) {
        unsigned v = lmax[i];
        if (v != ENC_NEG_INF) atomicMax(&pooled[i], v);
    }
}

// ---------------- softmax over [64,3] ----------------
__global__ void k_softmax(const unsigned* __restrict__ pooled, void* __restrict__ out,
                          const int* __restrict__ flags) {
    int g = threadIdx.x;
    if (g >= 64) return;
    int bf = flags[0];
    float a = fdec(pooled[g * 3 + 0]);
    float b = fdec(pooled[g * 3 + 1]);
    float c = fdec(pooled[g * 3 + 2]);
    float m = fmaxf(a, fmaxf(b, c));
    float ea = __expf(a - m), eb = __expf(b - m), ec = __expf(c - m);
    float s = 1.0f / (ea + eb + ec);
    if (bf) {
        __hip_bfloat16* o = (__hip_bfloat16*)out;
        o[g * 3 + 0] = __float2bfloat16(ea * s);
        o[g * 3 + 1] = __float2bfloat16(eb * s);
        o[g * 3 + 2] = __float2bfloat16(ec * s);
    } else {
        float* o = (float*)out;
        o[g * 3 + 0] = ea * s;
        o[g * 3 + 1] = eb * s;
        o[g * 3 + 2] = ec * s;
    }
}

extern "C" void kernel_launch(void* const* d_in, const int* in_sizes, int n_in,
                              void* d_out, int out_size, void* d_ws, size_t ws_size,
                              hipStream_t stream) {
    const void* x = d_in[0];
    const int* ei = (const int*)d_in[1];
    const int* batch = (const int*)d_in[2];
    const void* W1 = d_in[3];
    const void* b1 = d_in[4];
    const void* W2 = d_in[5];
    const void* b2 = d_in[6];
    const void* W3 = d_in[7];
    const void* b3 = d_in[8];
    const void* Wo = d_in[9];
    const void* bo = d_in[10];

    const int N = in_sizes[0] / 36;
    const int E = in_sizes[1] / 2;

    // ---- workspace carve ----
    char* ws = (char*)d_ws;
    size_t off = 0;
    auto carve = [&](size_t bytes) {
        char* p = ws + off;
        off = (off + bytes + 255) & ~(size_t)255;
        return p;
    };
    int* flags = (int*)carve(16);
    float* dinv = (float*)carve((size_t)N * 4);
    int* cnt = (int*)carve((size_t)N * 4);
    int* rowptr = (int*)carve((size_t)(N + 1) * 4);
    int2* ep = (int2*)carve((size_t)E * 8);  // interleaved (src, weight)
    unsigned* pooled = (unsigned*)carve(768);
    char* R1 = carve((size_t)N * 304);  // A1 f32 s76 | A2 f32 s76 | T3 f32 s76
    char* R2 = carve((size_t)N * 304);  // H1 f32 s76 | H2 bf16 s152 | Y3 f32 s76

    const int B = 256;

    // 0. dtype detection
    k_detect<<<1, 256, 0, stream>>>((const unsigned*)x, (const unsigned*)ei, flags);

    // 1. CSR build
    k_zero<<<DIV_UP(N, B), B, 0, stream>>>(cnt, N);
    k_hist<<<DIV_UP(E, B), B, 0, stream>>>(ei, cnt, flags, E);
    k_dinvc<<<DIV_UP(N, B), B, 0, stream>>>(cnt, dinv, N);
    k_scan<<<1, 1024, 0, stream>>>(cnt, rowptr, N);
    k_zero<<<DIV_UP(N, B), B, 0, stream>>>(cnt, N);
    k_fill<<<DIV_UP(E, B), B, 0, stream>>>(ei, rowptr, cnt, ep, dinv, flags, E);

    // 2. layer 1: aggregate x (36) -> A1, GEMM 36->75 relu -> H1
    k_agg<true><<<DIV_UP(N, 4), B, 0, stream>>>(x, 36, (float*)R1, 76, 36, rowptr, ep, dinv, flags,
                                                N);
    k_gemm<36, 75, 5, true, true, false, false>
        <<<DIV_UP(N, 64), B, 0, stream>>>(R1, 76, R2, 76, W1, b1, flags, N);

    // 3. layer 2: aggregate H1 (75) -> A2, GEMM 75->150 relu -> H2 (bf16)
    k_agg<false><<<DIV_UP(N, 4), B, 0, stream>>>(R2, 76, (float*)R1, 76, 75, rowptr, ep, dinv,
                                                 flags, N);
    k_gemm<75, 150, 10, true, true, false, true>
        <<<DIV_UP(N, 64), B, 0, stream>>>(R1, 76, R2, 152, W2, b2, flags, N);

    // 4. layer 3: GEMM 150->50 (no act) -> T3, aggregate (50) -> Y3
    k_gemm<150, 50, 4, false, false, true, false>
        <<<DIV_UP(N, 64), B, 0, stream>>>(R2, 152, R1, 76, W3, nullptr, flags, N);
    k_agg<false><<<DIV_UP(N, 4), B, 0, stream>>>(R1, 76, (float*)R2, 76, 50, rowptr, ep, dinv,
                                                 flags, N);

    // 5. head + pooling + softmax
    k_pool_init<<<1, 192, 0, stream>>>(pooled);
    k_head<<<DIV_UP(N, B), B, 0, stream>>>((const float*)R2, 76, b3, Wo, bo, batch, pooled, flags,
                                           N);
    k_softmax<<<1, 64, 0, stream>>>(pooled, d_out, flags);
}